// Round 2
// baseline (233.284 us; speedup 1.0000x reference)
//
#include <hip/hip_runtime.h>
#include <hip/hip_bf16.h>

#define NBATCH 32
#define NG 1024
#define DM 256

typedef short bf16x8 __attribute__((ext_vector_type(8)));
typedef float f32x4 __attribute__((ext_vector_type(4)));
typedef unsigned short u16x4 __attribute__((ext_vector_type(4)));
typedef unsigned short u16x8 __attribute__((ext_vector_type(8)));

static __device__ __forceinline__ unsigned short f2bf(float f) {
    __hip_bfloat16 h = __float2bfloat16(f);
    return *reinterpret_cast<unsigned short*>(&h);
}

// ---------------------------------------------------------------------------
// Kernel A: q/k/v projections.
// grid: 1024 blocks = b(32) x kt(8 row-tiles of 128) x dt(4 col-tiles of 64)
// block: 256 threads (4 waves); wave w owns rows [w*32, w*32+32) of the tile.
// Outputs:
//   sigq  f32  [b][n][256]         = sigmoid(q)
//   Pt    bf16 [b][512][1024]      row 2d = exp(k)*v, row 2d+1 = exp(k)
//   (Pt is the B^T operand of the main GEMM, pair-interleaved)
// ---------------------------------------------------------------------------

static __device__ __forceinline__ void gemm_tile(
    const float* __restrict__ Xrow,   // X + (b*NG + kt*128)*DM
    const float* __restrict__ Wt,     // W + dt*64*DM  (row-major [e][d])
    int tid, f32x4 (&acc)[2][4],
    unsigned short* lds_a, unsigned short* lds_w)
{
    const int lane = tid & 63, wv = tid >> 6;
    const int l15 = lane & 15, lhi = lane >> 4;
    const int arow = tid >> 1, ac0 = (tid & 1) << 5;   // A stage: 128x64, 32 f32/thr
    const int wrow = tid >> 2, wc0 = (tid & 3) << 4;   // W stage: 64x64, 16 f32/thr

    #pragma unroll
    for (int mi = 0; mi < 2; ++mi)
        #pragma unroll
        for (int ni = 0; ni < 4; ++ni)
            acc[mi][ni] = (f32x4){0.f, 0.f, 0.f, 0.f};

    for (int ks = 0; ks < 4; ++ks) {
        const float* asrc = Xrow + (size_t)arow * DM + ks * 64 + ac0;
        #pragma unroll
        for (int j = 0; j < 8; ++j) {
            float4 v = *(const float4*)(asrc + 4 * j);
            u16x4 p = { f2bf(v.x), f2bf(v.y), f2bf(v.z), f2bf(v.w) };
            *(u16x4*)&lds_a[arow * 72 + ac0 + 4 * j] = p;
        }
        const float* wsrc = Wt + (size_t)wrow * DM + ks * 64 + wc0;
        #pragma unroll
        for (int j = 0; j < 4; ++j) {
            float4 v = *(const float4*)(wsrc + 4 * j);
            u16x4 p = { f2bf(v.x), f2bf(v.y), f2bf(v.z), f2bf(v.w) };
            *(u16x4*)&lds_w[wrow * 72 + wc0 + 4 * j] = p;
        }
        __syncthreads();
        #pragma unroll
        for (int kk = 0; kk < 2; ++kk) {
            const int kb = kk * 32 + lhi * 8;
            bf16x8 bfr[4];
            #pragma unroll
            for (int ni = 0; ni < 4; ++ni)
                bfr[ni] = *(const bf16x8*)&lds_w[(ni * 16 + l15) * 72 + kb];
            #pragma unroll
            for (int mi = 0; mi < 2; ++mi) {
                bf16x8 af = *(const bf16x8*)&lds_a[(wv * 32 + mi * 16 + l15) * 72 + kb];
                #pragma unroll
                for (int ni = 0; ni < 4; ++ni)
                    acc[mi][ni] = __builtin_amdgcn_mfma_f32_16x16x32_bf16(
                        af, bfr[ni], acc[mi][ni], 0, 0, 0);
            }
        }
        __syncthreads();
    }
}

__global__ __launch_bounds__(256) void proj_kernel(
    const float* __restrict__ query, const float* __restrict__ key_,
    const float* __restrict__ value,
    const float* __restrict__ Wq, const float* __restrict__ bq,
    const float* __restrict__ Wk, const float* __restrict__ bk,
    const float* __restrict__ Wv, const float* __restrict__ bv,
    float* __restrict__ sigq, unsigned short* __restrict__ Pt)
{
    __shared__ unsigned short lds_a[128 * 72];
    __shared__ unsigned short lds_w[64 * 72];

    const int bid = blockIdx.x;
    const int b  = bid >> 5;
    const int kt = (bid >> 2) & 7;
    const int dt = bid & 3;
    const int tid = threadIdx.x;
    const int w = tid >> 6, lane = tid & 63;
    const int l15 = lane & 15, lhi = lane >> 4;

    const float* xq = query + ((size_t)b * NG + kt * 128) * DM;
    const float* xk = key_  + ((size_t)b * NG + kt * 128) * DM;
    const float* xv = value + ((size_t)b * NG + kt * 128) * DM;

    // ---- q projection + sigmoid store ----
    f32x4 aq[2][4];
    gemm_tile(xq, Wq + dt * 64 * DM, tid, aq, lds_a, lds_w);
    #pragma unroll
    for (int mi = 0; mi < 2; ++mi)
        #pragma unroll
        for (int ni = 0; ni < 4; ++ni) {
            const int colg = dt * 64 + ni * 16 + l15;
            const float bqs = bq[colg];
            #pragma unroll
            for (int r = 0; r < 4; ++r) {
                const int n = kt * 128 + w * 32 + mi * 16 + lhi * 4 + r;
                const float qv = aq[mi][ni][r] + bqs;
                sigq[((size_t)b * NG + n) * DM + colg] = 1.0f / (1.0f + __expf(-qv));
            }
        }

    // ---- k and v projections ----
    f32x4 ak[2][4], av[2][4];
    gemm_tile(xk, Wk + dt * 64 * DM, tid, ak, lds_a, lds_w);
    gemm_tile(xv, Wv + dt * 64 * DM, tid, av, lds_a, lds_w);

    #pragma unroll
    for (int mi = 0; mi < 2; ++mi)
        #pragma unroll
        for (int ni = 0; ni < 4; ++ni) {
            const int colg = dt * 64 + ni * 16 + l15;
            const float bks = bk[colg], bvs = bv[colg];
            unsigned short p1[4], p2[4];
            #pragma unroll
            for (int r = 0; r < 4; ++r) {
                const float ek = __expf(ak[mi][ni][r] + bks);
                const float vv = av[mi][ni][r] + bvs;
                p1[r] = f2bf(ek * vv);
                p2[r] = f2bf(ek);
            }
            const int kk0 = kt * 128 + w * 32 + mi * 16 + lhi * 4;
            *(u16x4*)&Pt[((size_t)b * 512 + 2 * colg    ) * NG + kk0] =
                (u16x4){p1[0], p1[1], p1[2], p1[3]};
            *(u16x4*)&Pt[((size_t)b * 512 + 2 * colg + 1) * NG + kk0] =
                (u16x4){p2[0], p2[1], p2[2], p2[3]};
        }
}

// ---------------------------------------------------------------------------
// Kernel B: out = sigmoid(q) * (E @ (expK*v)) / (E @ expK + 1e-8)
// E[m][k] = exp2(sc * dist[b][m][k]) computed on the fly during staging.
// One fused GEMM: M=1024, N=512 (num/den interleaved), K=1024 per batch.
// grid: 1024 blocks = b(32) x m(8) x n(4); tile 128x128, BK=64.
// XCD-chunked swizzle: consecutive logical blocks (same batch / m-panel)
// land on the same XCD -> dist tiles & Pt are L2-hits for the n-siblings.
// ---------------------------------------------------------------------------
__global__ __launch_bounds__(256) void attn_kernel(
    const float* __restrict__ dist, const unsigned short* __restrict__ Pt,
    const float* __restrict__ sigq, const float* __restrict__ alpha_raw,
    float* __restrict__ out)
{
    __shared__ unsigned short lds_a[128 * 72];
    __shared__ unsigned short lds_b[128 * 72];

    const int bid = blockIdx.x;
    const int l = (bid & 7) * 128 + (bid >> 3);   // bijective XCD-chunk swizzle (1024 % 8 == 0)
    const int b = l >> 5;
    const int m = (l >> 2) & 7;
    const int n = l & 3;

    const int tid = threadIdx.x;
    const int wv = tid >> 6, lane = tid & 63;
    const int wm = wv >> 1, wn = wv & 1;
    const int l15 = lane & 15, lhi = lane >> 4;

    const float ar = alpha_raw[0];
    const float alpha = log1pf(__expf(ar)) + 1e-6f;
    const float sc = -alpha * 10.0f * 1.44269504088896f;  // exp(x)=exp2(x*log2e), log2(1024)=10

    const int srow = tid >> 1;           // 0..127
    const int sc0  = (tid & 1) << 5;     // 0 or 32

    f32x4 acc[4][4];
    #pragma unroll
    for (int mi = 0; mi < 4; ++mi)
        #pragma unroll
        for (int ni = 0; ni < 4; ++ni)
            acc[mi][ni] = (f32x4){0.f, 0.f, 0.f, 0.f};

    const float* dbase = dist + ((size_t)b * NG + m * 128 + srow) * NG;
    const unsigned short* pbase = Pt + ((size_t)b * 512 + n * 128 + srow) * NG;

    for (int ks = 0; ks < 16; ++ks) {
        const int k0 = ks * 64;
        // stage A: dist -> exp2 -> bf16 (32 elements/thread)
        #pragma unroll
        for (int j = 0; j < 8; ++j) {
            float4 vd = *(const float4*)(dbase + k0 + sc0 + 4 * j);
            u16x4 pe = { f2bf(exp2f(sc * vd.x)), f2bf(exp2f(sc * vd.y)),
                         f2bf(exp2f(sc * vd.z)), f2bf(exp2f(sc * vd.w)) };
            *(u16x4*)&lds_a[srow * 72 + sc0 + 4 * j] = pe;
        }
        // stage B: Pt rows (already bf16, B^T layout), 32 shorts/thread
        #pragma unroll
        for (int j = 0; j < 4; ++j) {
            u16x8 vp = *(const u16x8*)(pbase + k0 + sc0 + 8 * j);
            *(u16x8*)&lds_b[srow * 72 + sc0 + 8 * j] = vp;
        }
        __syncthreads();
        #pragma unroll
        for (int kk = 0; kk < 2; ++kk) {
            const int kb = kk * 32 + lhi * 8;
            bf16x8 af[4], bfr[4];
            #pragma unroll
            for (int mi = 0; mi < 4; ++mi)
                af[mi] = *(const bf16x8*)&lds_a[(wm * 64 + mi * 16 + l15) * 72 + kb];
            #pragma unroll
            for (int ni = 0; ni < 4; ++ni)
                bfr[ni] = *(const bf16x8*)&lds_b[(wn * 64 + ni * 16 + l15) * 72 + kb];
            #pragma unroll
            for (int mi = 0; mi < 4; ++mi)
                #pragma unroll
                for (int ni = 0; ni < 4; ++ni)
                    acc[mi][ni] = __builtin_amdgcn_mfma_f32_16x16x32_bf16(
                        af[mi], bfr[ni], acc[mi][ni], 0, 0, 0);
        }
        __syncthreads();
    }

    // epilogue: even col = numerator, odd col = denominator (same d)
    const int parity = lane & 1;
    #pragma unroll
    for (int mi = 0; mi < 4; ++mi)
        #pragma unroll
        for (int ni = 0; ni < 4; ++ni)
            #pragma unroll
            for (int r = 0; r < 4; ++r) {
                const float own = acc[mi][ni][r];
                const float other = __shfl_xor(own, 1, 64);
                if (!parity) {
                    const int colg = n * 128 + wn * 64 + ni * 16 + l15;  // even
                    const int d = colg >> 1;
                    const int rowg = m * 128 + wm * 64 + mi * 16 + lhi * 4 + r;
                    const float res =
                        sigq[((size_t)b * NG + rowg) * DM + d] * (own / (other + 1e-8f));
                    out[((size_t)b * NG + rowg) * DM + d] = res;
                }
            }
}

extern "C" void kernel_launch(void* const* d_in, const int* in_sizes, int n_in,
                              void* d_out, int out_size, void* d_ws, size_t ws_size,
                              hipStream_t stream) {
    const float* query = (const float*)d_in[0];
    const float* key_  = (const float*)d_in[1];
    const float* value = (const float*)d_in[2];
    const float* dist  = (const float*)d_in[3];
    const float* Wq = (const float*)d_in[4];
    const float* bq = (const float*)d_in[5];
    const float* Wk = (const float*)d_in[6];
    const float* bk = (const float*)d_in[7];
    const float* Wv = (const float*)d_in[8];
    const float* bv = (const float*)d_in[9];
    const float* alpha_raw = (const float*)d_in[10];
    float* out = (float*)d_out;

    // workspace: sigq f32 [32][1024][256] (33.55 MB), Pt bf16 [32][512][1024] (33.55 MB)
    float* sigq = (float*)d_ws;
    unsigned short* Pt =
        (unsigned short*)((char*)d_ws + (size_t)NBATCH * NG * DM * sizeof(float));

    proj_kernel<<<dim3(1024), dim3(256), 0, stream>>>(
        query, key_, value, Wq, bq, Wk, bk, Wv, bv, sigq, Pt);
    attn_kernel<<<dim3(1024), dim3(256), 0, stream>>>(
        dist, Pt, sigq, alpha_raw, out);
}

// Round 3
// 206.460 us; speedup vs baseline: 1.1299x; 1.1299x over previous
//
#include <hip/hip_runtime.h>
#include <hip/hip_bf16.h>

#define NBATCH 32
#define NG 1024
#define DM 256
#define HB 16   // batches per attn pass (ws budget: 2 x 32 MiB)

typedef short bf16x8 __attribute__((ext_vector_type(8)));
typedef float f32x4 __attribute__((ext_vector_type(4)));
typedef unsigned short u16x4 __attribute__((ext_vector_type(4)));
typedef unsigned short u16x8 __attribute__((ext_vector_type(8)));

static __device__ __forceinline__ unsigned short f2bf(float f) {
    __hip_bfloat16 h = __float2bfloat16(f);
    return *reinterpret_cast<unsigned short*>(&h);
}

// async global->LDS, 16B per lane. LDS dest must be wave-uniform (HW adds lane*16).
static __device__ __forceinline__ void gload16(const void* g, void* l) {
    __builtin_amdgcn_global_load_lds(
        (const __attribute__((address_space(1))) unsigned int*)g,
        (__attribute__((address_space(3))) unsigned int*)l, 16, 0, 0);
}

// ---------------------------------------------------------------------------
// Kernel A: q/k/v projections (unchanged structure from round 2; sigq -> d_out).
// ---------------------------------------------------------------------------
static __device__ __forceinline__ void gemm_tile(
    const float* __restrict__ Xrow, const float* __restrict__ Wt,
    int tid, f32x4 (&acc)[2][4],
    unsigned short* lds_a, unsigned short* lds_w)
{
    const int lane = tid & 63, wv = tid >> 6;
    const int l15 = lane & 15, lhi = lane >> 4;
    const int arow = tid >> 1, ac0 = (tid & 1) << 5;
    const int wrow = tid >> 2, wc0 = (tid & 3) << 4;

    #pragma unroll
    for (int mi = 0; mi < 2; ++mi)
        #pragma unroll
        for (int ni = 0; ni < 4; ++ni)
            acc[mi][ni] = (f32x4){0.f, 0.f, 0.f, 0.f};

    for (int ks = 0; ks < 4; ++ks) {
        const float* asrc = Xrow + (size_t)arow * DM + ks * 64 + ac0;
        #pragma unroll
        for (int j = 0; j < 8; ++j) {
            float4 v = *(const float4*)(asrc + 4 * j);
            u16x4 p = { f2bf(v.x), f2bf(v.y), f2bf(v.z), f2bf(v.w) };
            *(u16x4*)&lds_a[arow * 72 + ac0 + 4 * j] = p;
        }
        const float* wsrc = Wt + (size_t)wrow * DM + ks * 64 + wc0;
        #pragma unroll
        for (int j = 0; j < 4; ++j) {
            float4 v = *(const float4*)(wsrc + 4 * j);
            u16x4 p = { f2bf(v.x), f2bf(v.y), f2bf(v.z), f2bf(v.w) };
            *(u16x4*)&lds_w[wrow * 72 + wc0 + 4 * j] = p;
        }
        __syncthreads();
        #pragma unroll
        for (int kk = 0; kk < 2; ++kk) {
            const int kb = kk * 32 + lhi * 8;
            bf16x8 bfr[4];
            #pragma unroll
            for (int ni = 0; ni < 4; ++ni)
                bfr[ni] = *(const bf16x8*)&lds_w[(ni * 16 + l15) * 72 + kb];
            #pragma unroll
            for (int mi = 0; mi < 2; ++mi) {
                bf16x8 af = *(const bf16x8*)&lds_a[(wv * 32 + mi * 16 + l15) * 72 + kb];
                #pragma unroll
                for (int ni = 0; ni < 4; ++ni)
                    acc[mi][ni] = __builtin_amdgcn_mfma_f32_16x16x32_bf16(
                        af, bfr[ni], acc[mi][ni], 0, 0, 0);
            }
        }
        __syncthreads();
    }
}

__global__ __launch_bounds__(256) void proj_kernel(
    const float* __restrict__ query, const float* __restrict__ key_,
    const float* __restrict__ value,
    const float* __restrict__ Wq, const float* __restrict__ bq,
    const float* __restrict__ Wk, const float* __restrict__ bk,
    const float* __restrict__ Wv, const float* __restrict__ bv,
    float* __restrict__ sigq, unsigned short* __restrict__ Pt)
{
    __shared__ unsigned short lds_a[128 * 72];
    __shared__ unsigned short lds_w[64 * 72];

    const int bid = blockIdx.x;
    const int b  = bid >> 5;
    const int kt = (bid >> 2) & 7;
    const int dt = bid & 3;
    const int tid = threadIdx.x;
    const int w = tid >> 6, lane = tid & 63;
    const int l15 = lane & 15, lhi = lane >> 4;

    const float* xq = query + ((size_t)b * NG + kt * 128) * DM;
    const float* xk = key_  + ((size_t)b * NG + kt * 128) * DM;
    const float* xv = value + ((size_t)b * NG + kt * 128) * DM;

    f32x4 aq[2][4];
    gemm_tile(xq, Wq + dt * 64 * DM, tid, aq, lds_a, lds_w);
    #pragma unroll
    for (int mi = 0; mi < 2; ++mi)
        #pragma unroll
        for (int ni = 0; ni < 4; ++ni) {
            const int colg = dt * 64 + ni * 16 + l15;
            const float bqs = bq[colg];
            #pragma unroll
            for (int r = 0; r < 4; ++r) {
                const int nrow = kt * 128 + w * 32 + mi * 16 + lhi * 4 + r;
                const float qv = aq[mi][ni][r] + bqs;
                sigq[((size_t)b * NG + nrow) * DM + colg] = 1.0f / (1.0f + __expf(-qv));
            }
        }

    f32x4 ak[2][4], av[2][4];
    gemm_tile(xk, Wk + dt * 64 * DM, tid, ak, lds_a, lds_w);
    gemm_tile(xv, Wv + dt * 64 * DM, tid, av, lds_a, lds_w);

    #pragma unroll
    for (int mi = 0; mi < 2; ++mi)
        #pragma unroll
        for (int ni = 0; ni < 4; ++ni) {
            const int colg = dt * 64 + ni * 16 + l15;
            const float bks = bk[colg], bvs = bv[colg];
            unsigned short p1[4], p2[4];
            #pragma unroll
            for (int r = 0; r < 4; ++r) {
                const float ek = __expf(ak[mi][ni][r] + bks);
                const float vv = av[mi][ni][r] + bvs;
                p1[r] = f2bf(ek * vv);
                p2[r] = f2bf(ek);
            }
            const int kk0 = kt * 128 + w * 32 + mi * 16 + lhi * 4;
            *(u16x4*)&Pt[((size_t)b * 512 + 2 * colg    ) * NG + kk0] =
                (u16x4){p1[0], p1[1], p1[2], p1[3]};
            *(u16x4*)&Pt[((size_t)b * 512 + 2 * colg + 1) * NG + kk0] =
                (u16x4){p2[0], p2[1], p2[2], p2[3]};
        }
}

// ---------------------------------------------------------------------------
// Kernel B: exp_A = bf16(exp2(sc * dist)) for HB batches. Memory-bound.
// grid: HB*NG*NG/8/256 = 8192 blocks, 8 elems/thread.
// ---------------------------------------------------------------------------
__global__ __launch_bounds__(256) void exp_kernel(
    const float* __restrict__ dist, unsigned short* __restrict__ ea,
    const float* __restrict__ alpha_raw)
{
    const float alpha = log1pf(__expf(alpha_raw[0])) + 1e-6f;
    const float sc = -alpha * 10.0f * 1.44269504088896f;
    const size_t i8 = ((size_t)blockIdx.x * 256 + threadIdx.x) * 8;
    float4 v0 = *(const float4*)(dist + i8);
    float4 v1 = *(const float4*)(dist + i8 + 4);
    u16x8 o = { f2bf(exp2f(sc * v0.x)), f2bf(exp2f(sc * v0.y)),
                f2bf(exp2f(sc * v0.z)), f2bf(exp2f(sc * v0.w)),
                f2bf(exp2f(sc * v1.x)), f2bf(exp2f(sc * v1.y)),
                f2bf(exp2f(sc * v1.z)), f2bf(exp2f(sc * v1.w)) };
    *(u16x8*)(ea + i8) = o;
}

// ---------------------------------------------------------------------------
// Kernel C: pure bf16 GEMM, out = sigq * (num/den).
// A = exp_A [HB][1024][1024], B^T = Pt [HB][512][1024] (num/den interleaved).
// grid: 512 blocks = 16b x 8m x 4n; tile 128x128, BK=64, dbuf LDS (64 KiB).
// Staging: global_load_lds w16, linear LDS dest, inverse-swizzled global src;
// ds_read_b128 with matching XOR swizzle -> 2-way (free) bank aliasing.
// sigq lives in `out` (f32): per-element read-then-overwrite by one thread.
// ---------------------------------------------------------------------------
__global__ __launch_bounds__(256) void attn_kernel(
    const unsigned short* __restrict__ ea,
    const unsigned short* __restrict__ Pt,
    float* __restrict__ out)
{
    __shared__ __align__(128) unsigned short lds[2][2][128 * 64];

    const int bid = blockIdx.x;
    const int l = (bid & 7) * 64 + (bid >> 3);   // XCD-chunked, bijective (512%8==0)
    const int b = l >> 5;          // 0..15
    const int m = (l >> 2) & 7;
    const int n = l & 3;

    const int tid = threadIdx.x;
    const int w = tid >> 6, lane = tid & 63;
    const int wm = w >> 1, wn = w & 1;
    const int l15 = lane & 15, lhi = lane >> 4;
    const int lr = lane >> 3, cb = lane & 7;
    const int cbs = cb ^ lr;       // inverse-swizzled source colblock (XOR involution)

    const char* Abase = (const char*)(ea + ((size_t)b * NG + m * 128) * NG);
    const char* Bbase = (const char*)(Pt + ((size_t)b * 512 + n * 128) * NG);

    f32x4 acc[4][4];
    #pragma unroll
    for (int mi = 0; mi < 4; ++mi)
        #pragma unroll
        for (int ni = 0; ni < 4; ++ni)
            acc[mi][ni] = (f32x4){0.f, 0.f, 0.f, 0.f};

    // stage k-tile t into buf: per wave 4x1KiB chunks per operand (rows w*32..+32)
    auto STAGE = [&](int buf, int t) {
        #pragma unroll
        for (int i = 0; i < 4; ++i) {
            const int r = w * 32 + i * 8 + lr;          // tile row; r&7 == lr
            const size_t goff = (size_t)r * 2048 + t * 128 + cbs * 16;
            char* ldst = (char*)&lds[buf][0][0] + w * 4096 + i * 1024;
            gload16(Abase + goff, ldst);
            gload16(Bbase + goff, ldst + 16384);
        }
    };

    STAGE(0, 0);
    __syncthreads();

    int cur = 0;
    for (int t = 0; t < 16; ++t) {
        if (t < 15) STAGE(cur ^ 1, t + 1);
        const char* Ab = (const char*)&lds[cur][0][0];
        const char* Bb = (const char*)&lds[cur][1][0];
        #pragma unroll
        for (int kk = 0; kk < 2; ++kk) {
            const int bc = kk * 64 + lhi * 16;          // byte col within row
            bf16x8 af[4], bfr[4];
            #pragma unroll
            for (int mi = 0; mi < 4; ++mi) {
                const int tr = wm * 64 + mi * 16 + l15; // tr&7 == l15&7
                af[mi] = *(const bf16x8*)(Ab + ((tr * 128 + bc) ^ ((tr & 7) << 4)));
            }
            #pragma unroll
            for (int ni = 0; ni < 4; ++ni) {
                const int tr = wn * 64 + ni * 16 + l15;
                bfr[ni] = *(const bf16x8*)(Bb + ((tr * 128 + bc) ^ ((tr & 7) << 4)));
            }
            #pragma unroll
            for (int mi = 0; mi < 4; ++mi)
                #pragma unroll
                for (int ni = 0; ni < 4; ++ni)
                    acc[mi][ni] = __builtin_amdgcn_mfma_f32_16x16x32_bf16(
                        af[mi], bfr[ni], acc[mi][ni], 0, 0, 0);
        }
        __syncthreads();
        cur ^= 1;
    }

    // epilogue: even col = numerator, odd = denominator (same d)
    const int parity = lane & 1;
    #pragma unroll
    for (int mi = 0; mi < 4; ++mi)
        #pragma unroll
        for (int ni = 0; ni < 4; ++ni)
            #pragma unroll
            for (int r = 0; r < 4; ++r) {
                const float own = acc[mi][ni][r];
                const float other = __shfl_xor(own, 1, 64);
                if (!parity) {
                    const int colg = n * 128 + wn * 64 + ni * 16 + l15;  // even
                    const int d = colg >> 1;
                    const int rowg = m * 128 + wm * 64 + mi * 16 + lhi * 4 + r;
                    const size_t idx = ((size_t)b * NG + rowg) * DM + d;
                    out[idx] = out[idx] * (own / (other + 1e-8f));  // out holds sigq
                }
            }
}

extern "C" void kernel_launch(void* const* d_in, const int* in_sizes, int n_in,
                              void* d_out, int out_size, void* d_ws, size_t ws_size,
                              hipStream_t stream) {
    const float* query = (const float*)d_in[0];
    const float* key_  = (const float*)d_in[1];
    const float* value = (const float*)d_in[2];
    const float* dist  = (const float*)d_in[3];
    const float* Wq = (const float*)d_in[4];
    const float* bq = (const float*)d_in[5];
    const float* Wk = (const float*)d_in[6];
    const float* bk = (const float*)d_in[7];
    const float* Wv = (const float*)d_in[8];
    const float* bv = (const float*)d_in[9];
    const float* alpha_raw = (const float*)d_in[10];
    float* out = (float*)d_out;

    // ws (64 MiB, proven): Pt bf16 [32][512][1024] | exp_A bf16 [HB][1024][1024]
    unsigned short* Pt = (unsigned short*)d_ws;
    unsigned short* exp_buf =
        (unsigned short*)((char*)d_ws + (size_t)NBATCH * 512 * NG * sizeof(unsigned short));

    // sigmoid(q) is staged in d_out; proj fully rewrites it every call.
    proj_kernel<<<dim3(1024), dim3(256), 0, stream>>>(
        query, key_, value, Wq, bq, Wk, bk, Wv, bv, out, Pt);

    for (int h = 0; h < 2; ++h) {
        exp_kernel<<<dim3(8192), dim3(256), 0, stream>>>(
            dist + (size_t)h * HB * NG * NG, exp_buf, alpha_raw);
        attn_kernel<<<dim3(512), dim3(256), 0, stream>>>(
            exp_buf, Pt + (size_t)h * HB * 512 * NG, out + (size_t)h * HB * NG * DM);
    }
}

// Round 4
// 203.295 us; speedup vs baseline: 1.1475x; 1.0156x over previous
//
#include <hip/hip_runtime.h>
#include <hip/hip_bf16.h>

#define NBATCH 32
#define NG 1024
#define DM 256
#define HB 16   // batches per attn pass (ws budget: 2 x 32 MiB)

typedef short bf16x8 __attribute__((ext_vector_type(8)));
typedef float f32x4 __attribute__((ext_vector_type(4)));
typedef unsigned short u16x4 __attribute__((ext_vector_type(4)));
typedef unsigned short u16x8 __attribute__((ext_vector_type(8)));

static __device__ __forceinline__ unsigned short f2bf(float f) {
    __hip_bfloat16 h = __float2bfloat16(f);
    return *reinterpret_cast<unsigned short*>(&h);
}

// async global->LDS, 16B per lane. LDS dest must be wave-uniform (HW adds lane*16).
static __device__ __forceinline__ void gload16(const void* g, void* l) {
    __builtin_amdgcn_global_load_lds(
        (const __attribute__((address_space(1))) unsigned int*)g,
        (__attribute__((address_space(3))) unsigned int*)l, 16, 0, 0);
}

// load 8 consecutive f32 from L2-resident W and pack to a bf16x8 fragment
static __device__ __forceinline__ bf16x8 ldW(const float* p) {
    float4 a = *(const float4*)p;
    float4 b = *(const float4*)(p + 4);
    union { u16x8 u; bf16x8 h; } t;
    t.u = (u16x8){ f2bf(a.x), f2bf(a.y), f2bf(a.z), f2bf(a.w),
                   f2bf(b.x), f2bf(b.y), f2bf(b.z), f2bf(b.w) };
    return t.h;
}

// ---------------------------------------------------------------------------
// Kernel A: q/k/v projections, v2.
// grid: 512 = b(32) x rt(16 row-tiles of 64). Block computes 64x256 for all
// three projections, reading X once. Wave w owns output cols [w*64, w*64+64).
// X staged full-K in LDS (bf16, [64][264] pad); W fragments read directly
// from global (L2-resident, 768 KB total) and packed in-reg.
// Pipeline: stage Xq | GEMM q + load Xk regs | GEMM k + load Xv regs | GEMM v.
// sigq -> d_out (f32); Pt bf16 [b][512][1024] (row 2d = exp(k)*v, 2d+1 = exp(k)).
// ---------------------------------------------------------------------------
__global__ __launch_bounds__(256) void proj_kernel(
    const float* __restrict__ query, const float* __restrict__ key_,
    const float* __restrict__ value,
    const float* __restrict__ Wq, const float* __restrict__ bq,
    const float* __restrict__ Wk, const float* __restrict__ bk,
    const float* __restrict__ Wv, const float* __restrict__ bv,
    float* __restrict__ sigq, unsigned short* __restrict__ Pt)
{
    __shared__ unsigned short xa[2][64 * 264];

    const int bid = blockIdx.x;
    const int b = bid >> 4, rt = bid & 15;
    const int tid = threadIdx.x;
    const int w = tid >> 6, lane = tid & 63;
    const int l15 = lane & 15, lhi = lane >> 4;

    // staging decomposition: thread covers row sr, 64-col chunk sc
    const int sr = tid >> 2;
    const int sc = (tid & 3) << 6;

    const size_t xoff = ((size_t)b * NG + rt * 64) * DM + (size_t)sr * DM + sc;
    const float* xq = query + xoff;
    const float* xk = key_  + xoff;
    const float* xv = value + xoff;

    auto GEMM = [&](const unsigned short* xbuf, const float* Wf, f32x4 (&acc)[4][4]) {
        #pragma unroll
        for (int mi = 0; mi < 4; ++mi)
            #pragma unroll
            for (int ni = 0; ni < 4; ++ni)
                acc[mi][ni] = (f32x4){0.f, 0.f, 0.f, 0.f};
        #pragma unroll
        for (int kk = 0; kk < 8; ++kk) {
            bf16x8 bfr[4], af[4];
            #pragma unroll
            for (int ni = 0; ni < 4; ++ni)
                bfr[ni] = ldW(Wf + (size_t)((w * 64 + ni * 16 + l15) << 8) + kk * 32 + lhi * 8);
            #pragma unroll
            for (int mi = 0; mi < 4; ++mi)
                af[mi] = *(const bf16x8*)&xbuf[(mi * 16 + l15) * 264 + kk * 32 + lhi * 8];
            #pragma unroll
            for (int mi = 0; mi < 4; ++mi)
                #pragma unroll
                for (int ni = 0; ni < 4; ++ni)
                    acc[mi][ni] = __builtin_amdgcn_mfma_f32_16x16x32_bf16(
                        af[mi], bfr[ni], acc[mi][ni], 0, 0, 0);
        }
    };

    // ---- phase 0: stage Xq -> buf0 ----
    {
        float4 t[16];
        #pragma unroll
        for (int j = 0; j < 16; ++j) t[j] = *(const float4*)(xq + 4 * j);
        #pragma unroll
        for (int j = 0; j < 16; ++j) {
            u16x4 p = { f2bf(t[j].x), f2bf(t[j].y), f2bf(t[j].z), f2bf(t[j].w) };
            *(u16x4*)&xa[0][sr * 264 + sc + 4 * j] = p;
        }
    }
    __syncthreads();

    // ---- phase 1: GEMM q (buf0) ; overlap: load Xk to regs ----
    float4 tk[16];
    #pragma unroll
    for (int j = 0; j < 16; ++j) tk[j] = *(const float4*)(xk + 4 * j);

    {
        f32x4 aq[4][4];
        GEMM(&xa[0][0], Wq, aq);
        // write Xk to buf1 first (so barrier isn't gated on sigq stores)
        #pragma unroll
        for (int j = 0; j < 16; ++j) {
            u16x4 p = { f2bf(tk[j].x), f2bf(tk[j].y), f2bf(tk[j].z), f2bf(tk[j].w) };
            *(u16x4*)&xa[1][sr * 264 + sc + 4 * j] = p;
        }
        #pragma unroll
        for (int ni = 0; ni < 4; ++ni) {
            const int colg = w * 64 + ni * 16 + l15;
            const float bqs = bq[colg];
            #pragma unroll
            for (int mi = 0; mi < 4; ++mi)
                #pragma unroll
                for (int r = 0; r < 4; ++r) {
                    const int rowg = rt * 64 + mi * 16 + lhi * 4 + r;
                    const float qv = aq[mi][ni][r] + bqs;
                    sigq[((size_t)b * NG + rowg) * DM + colg] = 1.0f / (1.0f + __expf(-qv));
                }
        }
    }
    __syncthreads();

    // ---- phase 2: GEMM k (buf1) ; overlap: load Xv to regs ----
    float4 tv[16];
    #pragma unroll
    for (int j = 0; j < 16; ++j) tv[j] = *(const float4*)(xv + 4 * j);

    f32x4 ak[4][4];
    GEMM(&xa[1][0], Wk, ak);
    #pragma unroll
    for (int j = 0; j < 16; ++j) {
        u16x4 p = { f2bf(tv[j].x), f2bf(tv[j].y), f2bf(tv[j].z), f2bf(tv[j].w) };
        *(u16x4*)&xa[0][sr * 264 + sc + 4 * j] = p;
    }
    __syncthreads();

    // ---- phase 3: GEMM v (buf0) ----
    f32x4 av[4][4];
    GEMM(&xa[0][0], Wv, av);

    // ---- epilogue: Pt (num/den interleaved, B^T layout) ----
    #pragma unroll
    for (int ni = 0; ni < 4; ++ni) {
        const int colg = w * 64 + ni * 16 + l15;
        const float bks = bk[colg], bvs = bv[colg];
        #pragma unroll
        for (int mi = 0; mi < 4; ++mi) {
            unsigned short p1[4], p2[4];
            #pragma unroll
            for (int r = 0; r < 4; ++r) {
                const float ek = __expf(ak[mi][ni][r] + bks);
                const float vv = av[mi][ni][r] + bvs;
                p1[r] = f2bf(ek * vv);
                p2[r] = f2bf(ek);
            }
            const int kk0 = rt * 64 + mi * 16 + lhi * 4;
            *(u16x4*)&Pt[((size_t)b * 512 + 2 * colg    ) * NG + kk0] =
                (u16x4){p1[0], p1[1], p1[2], p1[3]};
            *(u16x4*)&Pt[((size_t)b * 512 + 2 * colg + 1) * NG + kk0] =
                (u16x4){p2[0], p2[1], p2[2], p2[3]};
        }
    }
}

// ---------------------------------------------------------------------------
// Kernel B: exp_A = bf16(exp2(sc * dist)) for HB batches. Memory-bound.
// ---------------------------------------------------------------------------
__global__ __launch_bounds__(256) void exp_kernel(
    const float* __restrict__ dist, unsigned short* __restrict__ ea,
    const float* __restrict__ alpha_raw)
{
    const float alpha = log1pf(__expf(alpha_raw[0])) + 1e-6f;
    const float sc = -alpha * 10.0f * 1.44269504088896f;
    const size_t i8 = ((size_t)blockIdx.x * 256 + threadIdx.x) * 8;
    float4 v0 = *(const float4*)(dist + i8);
    float4 v1 = *(const float4*)(dist + i8 + 4);
    u16x8 o = { f2bf(exp2f(sc * v0.x)), f2bf(exp2f(sc * v0.y)),
                f2bf(exp2f(sc * v0.z)), f2bf(exp2f(sc * v0.w)),
                f2bf(exp2f(sc * v1.x)), f2bf(exp2f(sc * v1.y)),
                f2bf(exp2f(sc * v1.z)), f2bf(exp2f(sc * v1.w)) };
    *(u16x8*)(ea + i8) = o;
}

// ---------------------------------------------------------------------------
// Kernel C: pure bf16 GEMM, out = sigq * (num/den). (unchanged from round 3)
// ---------------------------------------------------------------------------
__global__ __launch_bounds__(256) void attn_kernel(
    const unsigned short* __restrict__ ea,
    const unsigned short* __restrict__ Pt,
    float* __restrict__ out)
{
    __shared__ __align__(128) unsigned short lds[2][2][128 * 64];

    const int bid = blockIdx.x;
    const int l = (bid & 7) * 64 + (bid >> 3);   // XCD-chunked, bijective (512%8==0)
    const int b = l >> 5;          // 0..15
    const int m = (l >> 2) & 7;
    const int n = l & 3;

    const int tid = threadIdx.x;
    const int w = tid >> 6, lane = tid & 63;
    const int wm = w >> 1, wn = w & 1;
    const int l15 = lane & 15, lhi = lane >> 4;
    const int lr = lane >> 3, cb = lane & 7;
    const int cbs = cb ^ lr;       // inverse-swizzled source colblock (XOR involution)

    const char* Abase = (const char*)(ea + ((size_t)b * NG + m * 128) * NG);
    const char* Bbase = (const char*)(Pt + ((size_t)b * 512 + n * 128) * NG);

    f32x4 acc[4][4];
    #pragma unroll
    for (int mi = 0; mi < 4; ++mi)
        #pragma unroll
        for (int ni = 0; ni < 4; ++ni)
            acc[mi][ni] = (f32x4){0.f, 0.f, 0.f, 0.f};

    auto STAGE = [&](int buf, int t) {
        #pragma unroll
        for (int i = 0; i < 4; ++i) {
            const int r = w * 32 + i * 8 + lr;          // tile row; r&7 == lr
            const size_t goff = (size_t)r * 2048 + t * 128 + cbs * 16;
            char* ldst = (char*)&lds[buf][0][0] + w * 4096 + i * 1024;
            gload16(Abase + goff, ldst);
            gload16(Bbase + goff, ldst + 16384);
        }
    };

    STAGE(0, 0);
    __syncthreads();

    int cur = 0;
    for (int t = 0; t < 16; ++t) {
        if (t < 15) STAGE(cur ^ 1, t + 1);
        const char* Ab = (const char*)&lds[cur][0][0];
        const char* Bb = (const char*)&lds[cur][1][0];
        #pragma unroll
        for (int kk = 0; kk < 2; ++kk) {
            const int bc = kk * 64 + lhi * 16;          // byte col within row
            bf16x8 af[4], bfr[4];
            #pragma unroll
            for (int mi = 0; mi < 4; ++mi) {
                const int tr = wm * 64 + mi * 16 + l15; // tr&7 == l15&7
                af[mi] = *(const bf16x8*)(Ab + ((tr * 128 + bc) ^ ((tr & 7) << 4)));
            }
            #pragma unroll
            for (int ni = 0; ni < 4; ++ni) {
                const int tr = wn * 64 + ni * 16 + l15;
                bfr[ni] = *(const bf16x8*)(Bb + ((tr * 128 + bc) ^ ((tr & 7) << 4)));
            }
            #pragma unroll
            for (int mi = 0; mi < 4; ++mi)
                #pragma unroll
                for (int ni = 0; ni < 4; ++ni)
                    acc[mi][ni] = __builtin_amdgcn_mfma_f32_16x16x32_bf16(
                        af[mi], bfr[ni], acc[mi][ni], 0, 0, 0);
        }
        __syncthreads();
        cur ^= 1;
    }

    const int parity = lane & 1;
    #pragma unroll
    for (int mi = 0; mi < 4; ++mi)
        #pragma unroll
        for (int ni = 0; ni < 4; ++ni)
            #pragma unroll
            for (int r = 0; r < 4; ++r) {
                const float own = acc[mi][ni][r];
                const float other = __shfl_xor(own, 1, 64);
                if (!parity) {
                    const int colg = n * 128 + wn * 64 + ni * 16 + l15;  // even
                    const int d = colg >> 1;
                    const int rowg = m * 128 + wm * 64 + mi * 16 + lhi * 4 + r;
                    const size_t idx = ((size_t)b * NG + rowg) * DM + d;
                    out[idx] = out[idx] * (own / (other + 1e-8f));  // out holds sigq
                }
            }
}

extern "C" void kernel_launch(void* const* d_in, const int* in_sizes, int n_in,
                              void* d_out, int out_size, void* d_ws, size_t ws_size,
                              hipStream_t stream) {
    const float* query = (const float*)d_in[0];
    const float* key_  = (const float*)d_in[1];
    const float* value = (const float*)d_in[2];
    const float* dist  = (const float*)d_in[3];
    const float* Wq = (const float*)d_in[4];
    const float* bq = (const float*)d_in[5];
    const float* Wk = (const float*)d_in[6];
    const float* bk = (const float*)d_in[7];
    const float* Wv = (const float*)d_in[8];
    const float* bv = (const float*)d_in[9];
    const float* alpha_raw = (const float*)d_in[10];
    float* out = (float*)d_out;

    // ws (64 MiB, proven): Pt bf16 [32][512][1024] | exp_A bf16 [HB][1024][1024]
    unsigned short* Pt = (unsigned short*)d_ws;
    unsigned short* exp_buf =
        (unsigned short*)((char*)d_ws + (size_t)NBATCH * 512 * NG * sizeof(unsigned short));

    // sigmoid(q) is staged in d_out; proj fully rewrites it every call.
    proj_kernel<<<dim3(512), dim3(256), 0, stream>>>(
        query, key_, value, Wq, bq, Wk, bk, Wv, bv, out, Pt);

    for (int h = 0; h < 2; ++h) {
        exp_kernel<<<dim3(8192), dim3(256), 0, stream>>>(
            dist + (size_t)h * HB * NG * NG, exp_buf, alpha_raw);
        attn_kernel<<<dim3(512), dim3(256), 0, stream>>>(
            exp_buf, Pt + (size_t)h * HB * 512 * NG, out + (size_t)h * HB * NG * DM);
    }
}